// Round 5
// baseline (1035.994 us; speedup 1.0000x reference)
//
#include <hip/hip_runtime.h>
#include <math.h>

typedef unsigned short u16;
typedef unsigned int u32;
typedef __attribute__((ext_vector_type(8))) short bf16x8;
typedef __attribute__((ext_vector_type(4))) float f32x4;

#define Bx 1024
#define Lx 200
#define Dx 128
#define FFx 512
#define Mx (Bx*Lx)
#define PVP 232   // P/V^T LDS row stride (u16)
#define LNP 136   // ts row stride (u16): 272B = 16B*17 -> conflict-free b128 row reads

__device__ __forceinline__ u16 f2bf(float f) {
  u32 u = __float_as_uint(f);
  u32 r = (u + 0x7fffu + ((u >> 16) & 1u)) >> 16;
  return (u16)r;
}

// fast GELU: tanh form, v*sigmoid(1.59577v + 0.0713548 v^3).
// |err| vs exact erf-gelu < 1e-4 for |v|<2 (pre-act sigma~0.23) — below bf16 eps.
__device__ __forceinline__ float gelu_f(float v) {
  float z = v * fmaf(v * v, 0.0713548163f, 1.5957691216f);
  float e = __expf(-z);
  return v * __builtin_amdgcn_rcpf(1.0f + e);
}

union BFCV { u32 u[4]; bf16x8 h; };

// ---------------- weight convert: fp32 [K][N] -> bf16 fragment order ----------------
// dst: [n_tile][k_step][lane][8], val = src[kst*32 + (lane>>4)*8 + j][ntile*16 + (lane&15)]
__global__ void k_cvt(const float* __restrict__ src, u16* __restrict__ dst,
                      int N, int k_steps) {
  int id = blockIdx.x * 256 + threadIdx.x;
  int lane = id & 63;
  int rest = id >> 6;
  int kst = rest % k_steps;
  int ntile = rest / k_steps;
  int n = ntile * 16 + (lane & 15);
  int kb = kst * 32 + ((lane >> 4) << 3);
  const float* sp = src + (size_t)kb * N + n;
  u32 w[4];
  #pragma unroll
  for (int j = 0; j < 4; ++j) {
    u32 lo = f2bf(sp[(size_t)(2 * j) * N]);
    u32 hi = f2bf(sp[(size_t)(2 * j + 1) * N]);
    w[j] = lo | (hi << 16);
  }
  ((uint4*)dst)[id] = make_uint4(w[0], w[1], w[2], w[3]);
}

// ---- LN core: lane (quad,l15) owns one row; v[32] = its col slice kst*32+quad*8..+8.
// Row stats reduced across the 4 quad-lanes via shfl_xor(16/32). Packs af[] A-frags.
__device__ __forceinline__ void ln_pack(const float v[32],
                                        const float* __restrict__ ln_w,
                                        const float* __restrict__ ln_b,
                                        int quad, bf16x8 af[4]) {
  float s = 0.f, sq = 0.f;
  #pragma unroll
  for (int i = 0; i < 32; ++i) { s += v[i]; sq = fmaf(v[i], v[i], sq); }
  s  += __shfl_xor(s, 16);  s  += __shfl_xor(s, 32);
  sq += __shfl_xor(sq, 16); sq += __shfl_xor(sq, 32);
  float mu = s * 0.0078125f;
  float rr = rsqrtf(fmaf(-mu, mu, sq * 0.0078125f) + 1e-5f);
  #pragma unroll
  for (int kst = 0; kst < 4; ++kst) {
    const float* lwp = ln_w + kst * 32 + quad * 8;
    const float* lbp = ln_b + kst * 32 + quad * 8;
    float4 lw0 = *(const float4*)(lwp);
    float4 lw1 = *(const float4*)(lwp + 4);
    float4 lb0 = *(const float4*)(lbp);
    float4 lb1 = *(const float4*)(lbp + 4);
    float hw[8] = {lw0.x, lw0.y, lw0.z, lw0.w, lw1.x, lw1.y, lw1.z, lw1.w};
    float hb[8] = {lb0.x, lb0.y, lb0.z, lb0.w, lb1.x, lb1.y, lb1.z, lb1.w};
    BFCV cv;
    #pragma unroll
    for (int j = 0; j < 4; ++j) {
      float h0 = fmaf((v[kst * 8 + 2 * j]     - mu) * rr, hw[2 * j],     hb[2 * j]);
      float h1 = fmaf((v[kst * 8 + 2 * j + 1] - mu) * rr, hw[2 * j + 1], hb[2 * j + 1]);
      cv.u[j] = (u32)f2bf(h0) | ((u32)f2bf(h1) << 16);
    }
    af[kst] = cv.h;
  }
}

__device__ __forceinline__ void load_x32(const float* __restrict__ xr, float v[32]) {
  #pragma unroll
  for (int kst = 0; kst < 4; ++kst) {
    float4 a = *(const float4*)(xr + kst * 32);
    float4 b = *(const float4*)(xr + kst * 32 + 4);
    v[kst * 8 + 0] = a.x; v[kst * 8 + 1] = a.y; v[kst * 8 + 2] = a.z; v[kst * 8 + 3] = a.w;
    v[kst * 8 + 4] = b.x; v[kst * 8 + 5] = b.y; v[kst * 8 + 6] = b.z; v[kst * 8 + 7] = b.w;
  }
}

// ---------------- fused [embed +] LN + QKV GEMM (MFMA), register LN, no LDS ----------
// EMB=true (layer 0): x = tok[seq] + pos computed in-register, written to x for the
// residual path, and fed straight to LN — removes the separate k_embed kernel and
// its extra 104MB x read.
template <bool EMB>
__device__ __forceinline__ void qkv_body(
    const float* __restrict__ x, float* __restrict__ xw,
    const int* __restrict__ seqc, const float* __restrict__ tok,
    const float* __restrict__ pos,
    const float* __restrict__ ln_w, const float* __restrict__ ln_b,
    const u16* __restrict__ Wqkvs,
    const float* __restrict__ bq, const float* __restrict__ bk,
    const float* __restrict__ bv,
    u16* __restrict__ qo, u16* __restrict__ ko, u16* __restrict__ vo) {
  const int tid = threadIdx.x;
  const int row0 = blockIdx.x * 64;
  const int lane = tid & 63, wv = tid >> 6;
  const int l15 = lane & 15, quad = lane >> 4;
  const int m0 = wv * 16;
  const int gr_ln = row0 + m0 + l15;          // this lane's LN row (chunk-local)

  float v[32];
  if (EMB) {
    const int t = seqc[gr_ln];
    const int pl = gr_ln % 200;
    const float* tp = tok + (size_t)t * Dx + quad * 8;
    const float* pp = pos + (size_t)pl * Dx + quad * 8;
    float* xp = xw + (size_t)gr_ln * Dx + quad * 8;
    #pragma unroll
    for (int kst = 0; kst < 4; ++kst) {
      float4 a = *(const float4*)(tp + kst * 32);
      float4 b = *(const float4*)(tp + kst * 32 + 4);
      float4 p0 = *(const float4*)(pp + kst * 32);
      float4 p1 = *(const float4*)(pp + kst * 32 + 4);
      a.x += p0.x; a.y += p0.y; a.z += p0.z; a.w += p0.w;
      b.x += p1.x; b.y += p1.y; b.z += p1.z; b.w += p1.w;
      *(float4*)(xp + kst * 32)     = a;
      *(float4*)(xp + kst * 32 + 4) = b;
      v[kst * 8 + 0] = a.x; v[kst * 8 + 1] = a.y; v[kst * 8 + 2] = a.z; v[kst * 8 + 3] = a.w;
      v[kst * 8 + 4] = b.x; v[kst * 8 + 5] = b.y; v[kst * 8 + 6] = b.z; v[kst * 8 + 7] = b.w;
    }
  } else {
    load_x32(x + (size_t)gr_ln * Dx + quad * 8, v);
  }
  bf16x8 af[4];
  ln_pack(v, ln_w, ln_b, quad, af);

  int bl[4], ll[4];
  #pragma unroll
  for (int r = 0; r < 4; ++r) {
    int gr = row0 + m0 + quad * 4 + r;
    bl[r] = gr / 200;
    ll[r] = gr - bl[r] * 200;
  }

  const float scale = 0.17677669529663687f;
  #pragma unroll
  for (int nt = 0; nt < 24; ++nt) {
    f32x4 acc = (f32x4){0.f, 0.f, 0.f, 0.f};
    const u16* wb = Wqkvs + ((size_t)(nt * 4) * 64 + lane) * 8;
    #pragma unroll
    for (int kst = 0; kst < 4; ++kst) {
      bf16x8 bfr = *(const bf16x8*)(wb + kst * 64 * 8);
      acc = __builtin_amdgcn_mfma_f32_16x16x32_bf16(af[kst], bfr, acc, 0, 0, 0);
    }
    const int col = (nt & 7) * 16 + l15;
    const int head = col >> 5, dk = col & 31;
    if (nt < 8) {
      float bb = bq[col];
      #pragma unroll
      for (int r = 0; r < 4; ++r)
        qo[((size_t)(bl[r] * 4 + head) * 200 + ll[r]) * 32 + dk] = f2bf((acc[r] + bb) * scale);
    } else if (nt < 16) {
      float bb = bk[col];
      #pragma unroll
      for (int r = 0; r < 4; ++r)
        ko[((size_t)(bl[r] * 4 + head) * 200 + ll[r]) * 32 + dk] = f2bf(acc[r] + bb);
    } else {
      float bb = bv[col];
      #pragma unroll
      for (int r = 0; r < 4; ++r)
        vo[((size_t)(bl[r] * 4 + head) * 200 + ll[r]) * 32 + dk] = f2bf(acc[r] + bb);
    }
  }
}

__global__ __launch_bounds__(256, 4)
void k_qkv(const float* __restrict__ x, const float* __restrict__ ln_w,
           const float* __restrict__ ln_b, const u16* __restrict__ Wqkvs,
           const float* __restrict__ bq, const float* __restrict__ bk,
           const float* __restrict__ bv,
           u16* __restrict__ qo, u16* __restrict__ ko, u16* __restrict__ vo) {
  qkv_body<false>(x, nullptr, nullptr, nullptr, nullptr, ln_w, ln_b, Wqkvs,
                  bq, bk, bv, qo, ko, vo);
}

__global__ __launch_bounds__(256, 4)
void k_qkv_emb(float* __restrict__ xw, const int* __restrict__ seqc,
               const float* __restrict__ tok, const float* __restrict__ pos,
               const float* __restrict__ ln_w, const float* __restrict__ ln_b,
               const u16* __restrict__ Wqkvs,
               const float* __restrict__ bq, const float* __restrict__ bk,
               const float* __restrict__ bv,
               u16* __restrict__ qo, u16* __restrict__ ko, u16* __restrict__ vo) {
  qkv_body<true>(nullptr, xw, seqc, tok, pos, ln_w, ln_b, Wqkvs,
                 bq, bk, bv, qo, ko, vo);
}

// ---------------- MFMA attention: one block per (b_local, head) ----------------
__global__ __launch_bounds__(256, 3)
void k_attn2(const u16* __restrict__ q, const u16* __restrict__ k,
             const u16* __restrict__ v, const int* __restrict__ seq,
             u16* __restrict__ attn) {
  __shared__ float smask[224];
  __shared__ __align__(16) u16 vt[32 * PVP];
  __shared__ __align__(16) u16 Pb[4][16 * PVP];
  const int tid = threadIdx.x;
  const int bl = blockIdx.x >> 2, head = blockIdx.x & 3;
  const int bh = blockIdx.x;
  const int lane = tid & 63, wv = tid >> 6;
  const int l15 = lane & 15, quad = lane >> 4;

  if (tid < 224)
    smask[tid] = (tid < 200 && seq[bl * 200 + tid] > 0) ? 0.f : -1e9f;
  // stage V^T into LDS: vt[dk][l]
  #pragma unroll 1
  for (int e = tid; e < 800; e += 256) {
    int l = e >> 2, g = (e & 3) * 8;
    uint4 pv = *(const uint4*)(v + ((size_t)bh * 200 + l) * 32 + g);
    const u16* pw = (const u16*)&pv;
    #pragma unroll
    for (int j = 0; j < 8; ++j) vt[(g + j) * PVP + l] = pw[j];
  }
  // zero V^T pad cols [200,232)
  #pragma unroll 1
  for (int e = tid; e < 1024; e += 256) {
    int rr = e >> 5, cc = 200 + (e & 31);
    vt[rr * PVP + cc] = 0;
  }
  __syncthreads();

  float msk[14];
  #pragma unroll
  for (int nt = 0; nt < 14; ++nt) msk[nt] = smask[nt * 16 + l15];

  const u16* qbase = q + (size_t)bh * 200 * 32;
  const u16* kbase = k + (size_t)bh * 200 * 32;
  u16* Pw = Pb[wv];

  #pragma unroll 1
  for (int mt = wv; mt < 13; mt += 4) {
    bf16x8 qf = *(const bf16x8*)(qbase + (mt * 16 + l15) * 32 + quad * 8);
    f32x4 s[14];
    #pragma unroll
    for (int nt = 0; nt < 14; ++nt) {
      bf16x8 kf = *(const bf16x8*)(kbase + (nt * 16 + l15) * 32 + quad * 8);
      s[nt] = __builtin_amdgcn_mfma_f32_16x16x32_bf16(qf, kf, (f32x4){0.f, 0.f, 0.f, 0.f}, 0, 0, 0);
    }
    // mask + row max
    float rmax[4] = {-1e30f, -1e30f, -1e30f, -1e30f};
    #pragma unroll
    for (int nt = 0; nt < 14; ++nt) {
      #pragma unroll
      for (int r = 0; r < 4; ++r) {
        s[nt][r] += msk[nt];
        rmax[r] = fmaxf(rmax[r], s[nt][r]);
      }
    }
    #pragma unroll
    for (int m = 1; m < 16; m <<= 1) {
      #pragma unroll
      for (int r = 0; r < 4; ++r) rmax[r] = fmaxf(rmax[r], __shfl_xor(rmax[r], m));
    }
    // exp + row sum
    float rsum[4] = {0.f, 0.f, 0.f, 0.f};
    #pragma unroll
    for (int nt = 0; nt < 14; ++nt) {
      #pragma unroll
      for (int r = 0; r < 4; ++r) {
        float p = __expf(s[nt][r] - rmax[r]);
        s[nt][r] = p;
        rsum[r] += p;
      }
    }
    #pragma unroll
    for (int m = 1; m < 16; m <<= 1) {
      #pragma unroll
      for (int r = 0; r < 4; ++r) rsum[r] += __shfl_xor(rsum[r], m);
    }
    float inv[4];
    #pragma unroll
    for (int r = 0; r < 4; ++r) inv[r] = 1.0f / rsum[r];
    // P -> wave-private LDS (bf16, unnormalized)
    #pragma unroll
    for (int nt = 0; nt < 14; ++nt) {
      #pragma unroll
      for (int r = 0; r < 4; ++r)
        Pw[(quad * 4 + r) * PVP + nt * 16 + l15] = f2bf(s[nt][r]);
    }
    __asm__ __volatile__("s_waitcnt lgkmcnt(0)" ::: "memory");
    // O = P @ V
    f32x4 o0 = (f32x4){0.f, 0.f, 0.f, 0.f}, o1 = (f32x4){0.f, 0.f, 0.f, 0.f};
    #pragma unroll
    for (int kst = 0; kst < 7; ++kst) {
      bf16x8 pf  = *(const bf16x8*)&Pw[l15 * PVP + kst * 32 + quad * 8];
      bf16x8 vf0 = *(const bf16x8*)&vt[l15 * PVP + kst * 32 + quad * 8];
      bf16x8 vf1 = *(const bf16x8*)&vt[(16 + l15) * PVP + kst * 32 + quad * 8];
      o0 = __builtin_amdgcn_mfma_f32_16x16x32_bf16(pf, vf0, o0, 0, 0, 0);
      o1 = __builtin_amdgcn_mfma_f32_16x16x32_bf16(pf, vf1, o1, 0, 0, 0);
    }
    #pragma unroll
    for (int r = 0; r < 4; ++r) {
      int row = mt * 16 + quad * 4 + r;
      if (row < 200) {
        u16* op = attn + ((size_t)bl * 200 + row) * 128 + head * 32;
        op[l15]      = f2bf(o0[r] * inv[r]);
        op[16 + l15] = f2bf(o1[r] * inv[r]);
      }
    }
  }
}

// ---------------- O-projection + residual (MFMA): x += a @ Wo + bo ----------------
__global__ __launch_bounds__(256, 4)
void k_oproj(const u16* __restrict__ a, const u16* __restrict__ Wos,
             const float* __restrict__ bo, float* __restrict__ x) {
  const int tid = threadIdx.x;
  const int lane = tid & 63, wv = tid >> 6;
  const int l15 = lane & 15, quad = lane >> 4;
  const size_t m0 = (size_t)blockIdx.x * 64 + wv * 16;
  f32x4 acc[8];
  #pragma unroll
  for (int i = 0; i < 8; ++i) acc[i] = (f32x4){0.f, 0.f, 0.f, 0.f};
  #pragma unroll
  for (int kst = 0; kst < 4; ++kst) {
    bf16x8 af = *(const bf16x8*)(a + (m0 + l15) * Dx + kst * 32 + quad * 8);
    const u16* wb = Wos + (kst * 64 + lane) * 8;
    #pragma unroll
    for (int nt = 0; nt < 8; ++nt) {
      bf16x8 bf = *(const bf16x8*)(wb + nt * (4 * 64 * 8));
      acc[nt] = __builtin_amdgcn_mfma_f32_16x16x32_bf16(af, bf, acc[nt], 0, 0, 0);
    }
  }
  #pragma unroll
  for (int nt = 0; nt < 8; ++nt) {
    int col = nt * 16 + l15;
    float bb = bo[col];
    #pragma unroll
    for (int r = 0; r < 4; ++r) {
      size_t idx = (m0 + quad * 4 + r) * Dx + col;
      x[idx] += acc[nt][r] + bb;
    }
  }
}

// ---------------- fused LN + FFN (MFMA): x += gelu(LN(x)@W1+b1)@W2 + b2 ----------------
// 512 threads / 8 waves / 128 rows. 2-D wave split: rg=wv>>1 owns 32 rows (2 row-tiles),
// cq=wv&1 owns half the N-tiles. Halves B-fragment LDS-read redundancy (8x -> 4x) —
// round-4 counters showed LDS reads (~2MB/block) as the longest pole. GELU output is
// exchanged between cq-partners through ts. Weights stream through ONE rolling 2x8KB
// double-buffer (W1 and W2 phases alternate through it) with async-split staging.
// LDS = 34816 (ts) + 16384 (wbuf) = 50 KB.
__global__ __launch_bounds__(512, 4)
void k_ffn(float* __restrict__ x, const float* __restrict__ ln_w,
           const float* __restrict__ ln_b,
           const u16* __restrict__ W1s, const float* __restrict__ b1,
           const u16* __restrict__ W2s, const float* __restrict__ b2) {
  __shared__ __align__(16) u16 ts[128 * LNP];
  __shared__ __align__(16) u16 wbuf[2 * 4096];
  const int tid = threadIdx.x;
  const size_t row0 = (size_t)blockIdx.x * 128;
  const int lane = tid & 63, wv = tid >> 6;           // wv in [0,8)
  const int l15 = lane & 15, quad = lane >> 4;
  const int rg = wv >> 1, cq = wv & 1;
  const int r0 = rg * 32;                             // wave's local row base

  // register LN for the wave's 2 row-tiles
  bf16x8 af[2][4];
  #pragma unroll
  for (int rt = 0; rt < 2; ++rt) {
    float v[32];
    load_x32(x + (row0 + r0 + rt * 16 + l15) * (size_t)Dx + quad * 8, v);
    ln_pack(v, ln_w, ln_b, quad, af[rt]);
  }

  // prologue: stage W1(ch0,kst0); each wave copies its 1KB nt-piece
  ((uint4*)wbuf)[tid] = ((const uint4*)(W1s + (size_t)(wv * 4) * 512))[lane];
  __syncthreads();

  f32x4 acc2[2][4];
  #pragma unroll
  for (int rt = 0; rt < 2; ++rt)
    #pragma unroll
    for (int j = 0; j < 4; ++j) acc2[rt][j] = (f32x4){0.f, 0.f, 0.f, 0.f};

  int pq = 0;   // rolling phase parity for wbuf
  #pragma unroll 1
  for (int ch = 0; ch < 4; ++ch) {
    // ---- GEMM1: 4 kst phases ----
    f32x4 acc1[2][4];
    #pragma unroll
    for (int rt = 0; rt < 2; ++rt)
      #pragma unroll
      for (int j = 0; j < 4; ++j) acc1[rt][j] = (f32x4){0.f, 0.f, 0.f, 0.f};
    #pragma unroll
    for (int kst = 0; kst < 4; ++kst) {
      uint4 stg;
      if (kst < 3)
        stg = ((const uint4*)(W1s + (size_t)((ch * 8 + wv) * 4 + kst + 1) * 512))[lane];
      else
        stg = ((const uint4*)(W2s + (size_t)(wv * 16 + ch * 4) * 512))[lane];
      const u16* wb = wbuf + (pq & 1) * 4096;
      bf16x8 bfr[4];
      #pragma unroll
      for (int j = 0; j < 4; ++j)
        bfr[j] = *(const bf16x8*)&wb[(cq * 4 + j) * 512 + lane * 8];
      #pragma unroll
      for (int j = 0; j < 4; ++j) {
        acc1[0][j] = __builtin_amdgcn_mfma_f32_16x16x32_bf16(af[0][kst], bfr[j], acc1[0][j], 0, 0, 0);
        acc1[1][j] = __builtin_amdgcn_mfma_f32_16x16x32_bf16(af[1][kst], bfr[j], acc1[1][j], 0, 0, 0);
      }
      if (kst == 3) {
        // gelu -> ts (wave's rows x its 64 ch-cols); read later by both cq partners
        #pragma unroll
        for (int rt = 0; rt < 2; ++rt)
          #pragma unroll
          for (int j = 0; j < 4; ++j) {
            const int col = (cq * 4 + j) * 16 + l15;
            float bb = b1[ch * 128 + col];
            #pragma unroll
            for (int r = 0; r < 4; ++r)
              ts[(r0 + rt * 16 + quad * 4 + r) * LNP + col] =
                  f2bf(gelu_f(acc1[rt][j][r] + bb));
          }
      }
      ((uint4*)(wbuf + ((pq + 1) & 1) * 4096))[tid] = stg;
      __syncthreads();
      ++pq;
    }
    // ---- GEMM2: 4 p phases (k-slices of this ch) ----
    #pragma unroll
    for (int p = 0; p < 4; ++p) {
      uint4 stg;
      bool have = true;
      if (p < 3)
        stg = ((const uint4*)(W2s + (size_t)(wv * 16 + ch * 4 + p + 1) * 512))[lane];
      else if (ch < 3)
        stg = ((const uint4*)(W1s + (size_t)(((ch + 1) * 8 + wv) * 4) * 512))[lane];
      else
        have = false;
      const u16* wb = wbuf + (pq & 1) * 4096;
      bf16x8 tf[2];
      #pragma unroll
      for (int rt = 0; rt < 2; ++rt)
        tf[rt] = *(const bf16x8*)&ts[(r0 + rt * 16 + l15) * LNP + p * 32 + quad * 8];
      bf16x8 bfr[4];
      #pragma unroll
      for (int j = 0; j < 4; ++j)
        bfr[j] = *(const bf16x8*)&wb[(cq * 4 + j) * 512 + lane * 8];
      #pragma unroll
      for (int j = 0; j < 4; ++j) {
        acc2[0][j] = __builtin_amdgcn_mfma_f32_16x16x32_bf16(tf[0], bfr[j], acc2[0][j], 0, 0, 0);
        acc2[1][j] = __builtin_amdgcn_mfma_f32_16x16x32_bf16(tf[1], bfr[j], acc2[1][j], 0, 0, 0);
      }
      if (have)
        ((uint4*)(wbuf + ((pq + 1) & 1) * 4096))[tid] = stg;
      __syncthreads();
      ++pq;
    }
  }
  // epilogue: x += acc2 + b2
  #pragma unroll
  for (int rt = 0; rt < 2; ++rt)
    #pragma unroll
    for (int j = 0; j < 4; ++j) {
      const int col = (cq * 4 + j) * 16 + l15;
      float bb = b2[col];
      #pragma unroll
      for (int r = 0; r < 4; ++r) {
        size_t idx = (row0 + r0 + rt * 16 + quad * 4 + r) * Dx + col;
        x[idx] += acc2[rt][j][r] + bb;
      }
    }
}

// ---------------- final FC (MFMA, split-K 32) ----------------
__global__ __launch_bounds__(256, 4)
void k_fc(const float* __restrict__ x, const u16* __restrict__ fcWs,
          float* __restrict__ part) {
  const int tid = threadIdx.x;
  const int lane = tid & 63, wv = tid >> 6;
  const int l15 = lane & 15, quad = lane >> 4;
  const int m0 = blockIdx.x * 64 + wv * 16;
  const int ky = blockIdx.y;
  f32x4 acc[8];
  #pragma unroll
  for (int i = 0; i < 8; ++i) acc[i] = (f32x4){0.f, 0.f, 0.f, 0.f};
  const float* xp = x + (size_t)(m0 + l15) * 25600 + quad * 8;
  #pragma unroll 1
  for (int kst = ky * 25; kst < ky * 25 + 25; ++kst) {
    float4 xa = *(const float4*)(xp + kst * 32);
    float4 xb2 = *(const float4*)(xp + kst * 32 + 4);
    bf16x8 af;
    af[0] = (short)f2bf(xa.x);  af[1] = (short)f2bf(xa.y);
    af[2] = (short)f2bf(xa.z);  af[3] = (short)f2bf(xa.w);
    af[4] = (short)f2bf(xb2.x); af[5] = (short)f2bf(xb2.y);
    af[6] = (short)f2bf(xb2.z); af[7] = (short)f2bf(xb2.w);
    const u16* wb = fcWs + ((size_t)kst * 64 + lane) * 8;
    #pragma unroll
    for (int nt = 0; nt < 8; ++nt) {
      bf16x8 bf = *(const bf16x8*)(wb + (size_t)nt * (800 * 64 * 8));
      acc[nt] = __builtin_amdgcn_mfma_f32_16x16x32_bf16(af, bf, acc[nt], 0, 0, 0);
    }
  }
  float* pp = part + (size_t)ky * (Bx * Dx);
  #pragma unroll
  for (int nt = 0; nt < 8; ++nt) {
    #pragma unroll
    for (int r = 0; r < 4; ++r) {
      pp[(size_t)(m0 + quad * 4 + r) * Dx + nt * 16 + l15] = acc[nt][r];
    }
  }
}

__global__ void k_fcred(const float* __restrict__ part, const float* __restrict__ fcb,
                        float* __restrict__ out) {
  int i = blockIdx.x * 256 + threadIdx.x;
  float s = fcb[i & 127];
  #pragma unroll
  for (int k = 0; k < 32; ++k) s += part[(size_t)k * (Bx * Dx) + i];
  out[i] = s;
}

extern "C" void kernel_launch(void* const* d_in, const int* in_sizes, int n_in,
                              void* d_out, int out_size, void* d_ws, size_t ws_size,
                              hipStream_t stream) {
  const int*   seq  = (const int*)d_in[0];
  const float* tok  = (const float*)d_in[1];
  const float* pos  = (const float*)d_in[2];
  const float* Wq   = (const float*)d_in[3];
  const float* bq   = (const float*)d_in[4];
  const float* Wk   = (const float*)d_in[5];
  const float* bk   = (const float*)d_in[6];
  const float* Wv   = (const float*)d_in[7];
  const float* bv   = (const float*)d_in[8];
  const float* Wo   = (const float*)d_in[9];
  const float* bo   = (const float*)d_in[10];
  const float* ln1w = (const float*)d_in[11];
  const float* ln1b = (const float*)d_in[12];
  const float* ln2w = (const float*)d_in[13];
  const float* ln2b = (const float*)d_in[14];
  const float* W1   = (const float*)d_in[15];
  const float* b1   = (const float*)d_in[16];
  const float* W2   = (const float*)d_in[17];
  const float* b2   = (const float*)d_in[18];
  const float* fcW  = (const float*)d_in[19];
  const float* fcb  = (const float*)d_in[20];
  float* out = (float*)d_out;

  char* ws = (char*)d_ws;
  const size_t XB = (size_t)Mx * Dx * 4;        // 104,857,600 B
  const size_t WBSZ = 7340032;                  // converted-weight region

  // adaptive batch chunking: 4 equal bf16 regions of (Bx/nc)*51200 B after x
  int nc = 4;
  for (int t = 1; t <= 4; t <<= 1) {
    size_t qsz = (size_t)(Bx / t) * 51200;
    if (XB + 4 * qsz + WBSZ <= ws_size) { nc = t; break; }
  }
  const int BC = Bx / nc;                        // batches per chunk
  const size_t qsz = (size_t)BC * 51200;

  float* x    = (float*)ws;
  u16* qb     = (u16*)(ws + XB);
  u16* kb     = (u16*)(ws + XB + qsz);
  u16* vb     = (u16*)(ws + XB + 2 * qsz);
  u16* ab     = (u16*)(ws + XB + 3 * qsz);
  float* part = (float*)(ws + XB);               // aliases q/k (dead by k_fc)
  char* WB    = ws + XB + 4 * qsz;
  u16* W1s0   = (u16*)(WB);
  u16* W1s1   = (u16*)(WB + 131072);
  u16* W2s0   = (u16*)(WB + 262144);
  u16* W2s1   = (u16*)(WB + 393216);
  u16* Wos0   = (u16*)(WB + 524288);
  u16* Wos1   = (u16*)(WB + 557056);
  u16* Wqkvs0 = (u16*)(WB + 589824);
  u16* Wqkvs1 = (u16*)(WB + 688128);
  u16* fcWs   = (u16*)(WB + 786432);

  // weight conversion to fragment-ordered bf16
  k_cvt<<<32, 256, 0, stream>>>(W1, W1s0, FFx, 4);
  k_cvt<<<32, 256, 0, stream>>>(W1 + Dx * FFx, W1s1, FFx, 4);
  k_cvt<<<32, 256, 0, stream>>>(W2, W2s0, Dx, 16);
  k_cvt<<<32, 256, 0, stream>>>(W2 + FFx * Dx, W2s1, Dx, 16);
  k_cvt<<<8, 256, 0, stream>>>(Wo, Wos0, Dx, 4);
  k_cvt<<<8, 256, 0, stream>>>(Wo + Dx * Dx, Wos1, Dx, 4);
  k_cvt<<<8, 256, 0, stream>>>(Wq, Wqkvs0, Dx, 4);
  k_cvt<<<8, 256, 0, stream>>>(Wk, Wqkvs0 + 16384, Dx, 4);
  k_cvt<<<8, 256, 0, stream>>>(Wv, Wqkvs0 + 32768, Dx, 4);
  k_cvt<<<8, 256, 0, stream>>>(Wq + Dx * Dx, Wqkvs1, Dx, 4);
  k_cvt<<<8, 256, 0, stream>>>(Wk + Dx * Dx, Wqkvs1 + 16384, Dx, 4);
  k_cvt<<<8, 256, 0, stream>>>(Wv + Dx * Dx, Wqkvs1 + 32768, Dx, 4);
  k_cvt<<<1600, 256, 0, stream>>>(fcW, fcWs, Dx, 800);

  const int cblk = BC * 200 / 64;   // 64-row blocks per chunk
  for (int i = 0; i < 2; ++i) {
    const u16* Wqkvs = (i == 0) ? Wqkvs0 : Wqkvs1;
    const u16* Wos   = (i == 0) ? Wos0 : Wos1;
    for (int c = 0; c < nc; ++c) {
      float* xc = x + (size_t)c * BC * 200 * 128;
      const int* seqc = seq + (size_t)c * BC * 200;
      if (i == 0)
        k_qkv_emb<<<cblk, 256, 0, stream>>>(xc, seqc, tok, pos,
                                            ln1w, ln1b, Wqkvs,
                                            bq, bk, bv, qb, kb, vb);
      else
        k_qkv<<<cblk, 256, 0, stream>>>(xc, ln1w + i * Dx, ln1b + i * Dx, Wqkvs,
                                        bq + i * Dx, bk + i * Dx, bv + i * Dx,
                                        qb, kb, vb);
      k_attn2<<<BC * 4, 256, 0, stream>>>(qb, kb, vb, seqc, ab);
      k_oproj<<<cblk, 256, 0, stream>>>(ab, Wos, bo + i * Dx, xc);
    }
    k_ffn<<<1600, 512, 0, stream>>>(x, ln2w + i * Dx, ln2b + i * Dx,
                                    (i == 0) ? W1s0 : W1s1, b1 + i * FFx,
                                    (i == 0) ? W2s0 : W2s1, b2 + i * Dx);
  }
  k_fc<<<dim3(16, 32), 256, 0, stream>>>(x, fcWs, part);
  k_fcred<<<512, 256, 0, stream>>>(part, fcb, out);
}

// Round 6
// 988.915 us; speedup vs baseline: 1.0476x; 1.0476x over previous
//
#include <hip/hip_runtime.h>
#include <math.h>

typedef unsigned short u16;
typedef unsigned int u32;
typedef __attribute__((ext_vector_type(8))) short bf16x8;
typedef __attribute__((ext_vector_type(4))) float f32x4;

#define Bx 1024
#define Lx 200
#define Dx 128
#define FFx 512
#define Mx (Bx*Lx)
#define PVP 232   // P/V^T LDS row stride (u16)
#define TSP 40    // ts row stride (u16): 32 cols + 8 pad; 2-way pattern (free)

__device__ __forceinline__ u16 f2bf(float f) {
  u32 u = __float_as_uint(f);
  u32 r = (u + 0x7fffu + ((u >> 16) & 1u)) >> 16;
  return (u16)r;
}

// fast GELU: tanh form, v*sigmoid(1.59577v + 0.0713548 v^3).
// |err| vs exact erf-gelu < 1e-4 for |v|<2 (pre-act sigma~0.23) — below bf16 eps.
__device__ __forceinline__ float gelu_f(float v) {
  float z = v * fmaf(v * v, 0.0713548163f, 1.5957691216f);
  float e = __expf(-z);
  return v * __builtin_amdgcn_rcpf(1.0f + e);
}

union BFCV { u32 u[4]; bf16x8 h; };

// ---------------- merged weight convert: fp32 [K][N] -> bf16 fragment order -------
// One launch for all 13 weight tensors (was 13 dependent dispatches on the critical
// path). dst: [n_tile][k_step][lane][8],
// val = src[kst*32 + (lane>>4)*8 + j][ntile*16 + (lane&15)]
struct CvtJobs {
  const float* src[13];
  u16* dst[13];
  int N[13];
  int ks[13];
  int bstart[14];
};

__global__ void k_cvt_all(CvtJobs J) {
  const int b = blockIdx.x;
  int j = 0;
  #pragma unroll 1
  while (b >= J.bstart[j + 1]) ++j;          // uniform per block (scalar)
  const float* __restrict__ src = J.src[j];
  u16* __restrict__ dst = J.dst[j];
  const int N = J.N[j], k_steps = J.ks[j];
  int id = (b - J.bstart[j]) * 256 + threadIdx.x;
  int lane = id & 63;
  int rest = id >> 6;
  int kst = rest % k_steps;
  int ntile = rest / k_steps;
  int n = ntile * 16 + (lane & 15);
  int kb = kst * 32 + ((lane >> 4) << 3);
  const float* sp = src + (size_t)kb * N + n;
  u32 w[4];
  #pragma unroll
  for (int jj = 0; jj < 4; ++jj) {
    u32 lo = f2bf(sp[(size_t)(2 * jj) * N]);
    u32 hi = f2bf(sp[(size_t)(2 * jj + 1) * N]);
    w[jj] = lo | (hi << 16);
  }
  ((uint4*)dst)[id] = make_uint4(w[0], w[1], w[2], w[3]);
}

// ---------------- embedding: x = tok[seq] + pos ----------------
__global__ void k_embed(const int* __restrict__ seq, const float* __restrict__ tok,
                        const float* __restrict__ pos, float* __restrict__ x) {
  const int i = blockIdx.x * 256 + threadIdx.x;
  const int row = i >> 5, c = i & 31;
  const int t = seq[row];
  const int l = row % Lx;
  const float4 a = ((const float4*)tok)[(size_t)t * 32 + c];
  const float4 p = ((const float4*)pos)[l * 32 + c];
  ((float4*)x)[i] = make_float4(a.x + p.x, a.y + p.y, a.z + p.z, a.w + p.w);
}

// ---- register layernorm: lane (quad,l15) owns row m0+l15, cols kst*32+quad*8..+8.
// Row stats reduced across the 4 quad-lanes via shfl_xor(16/32). Returns af[] A-frags.
__device__ __forceinline__ void reg_ln(const float* __restrict__ xr,
                                       const float* __restrict__ ln_w,
                                       const float* __restrict__ ln_b,
                                       int quad, bf16x8 af[4]) {
  float v[32];
  float s = 0.f, sq = 0.f;
  #pragma unroll
  for (int kst = 0; kst < 4; ++kst) {
    float4 a = *(const float4*)(xr + kst * 32);
    float4 b = *(const float4*)(xr + kst * 32 + 4);
    v[kst * 8 + 0] = a.x; v[kst * 8 + 1] = a.y; v[kst * 8 + 2] = a.z; v[kst * 8 + 3] = a.w;
    v[kst * 8 + 4] = b.x; v[kst * 8 + 5] = b.y; v[kst * 8 + 6] = b.z; v[kst * 8 + 7] = b.w;
  }
  #pragma unroll
  for (int i = 0; i < 32; ++i) { s += v[i]; sq = fmaf(v[i], v[i], sq); }
  s  += __shfl_xor(s, 16);  s  += __shfl_xor(s, 32);
  sq += __shfl_xor(sq, 16); sq += __shfl_xor(sq, 32);
  float mu = s * 0.0078125f;
  float rr = rsqrtf(fmaf(-mu, mu, sq * 0.0078125f) + 1e-5f);
  #pragma unroll
  for (int kst = 0; kst < 4; ++kst) {
    const float* lwp = ln_w + kst * 32 + quad * 8;
    const float* lbp = ln_b + kst * 32 + quad * 8;
    float4 lw0 = *(const float4*)(lwp);
    float4 lw1 = *(const float4*)(lwp + 4);
    float4 lb0 = *(const float4*)(lbp);
    float4 lb1 = *(const float4*)(lbp + 4);
    float hw[8] = {lw0.x, lw0.y, lw0.z, lw0.w, lw1.x, lw1.y, lw1.z, lw1.w};
    float hb[8] = {lb0.x, lb0.y, lb0.z, lb0.w, lb1.x, lb1.y, lb1.z, lb1.w};
    BFCV cv;
    #pragma unroll
    for (int j = 0; j < 4; ++j) {
      float h0 = fmaf((v[kst * 8 + 2 * j]     - mu) * rr, hw[2 * j],     hb[2 * j]);
      float h1 = fmaf((v[kst * 8 + 2 * j + 1] - mu) * rr, hw[2 * j + 1], hb[2 * j + 1]);
      cv.u[j] = (u32)f2bf(h0) | ((u32)f2bf(h1) << 16);
    }
    af[kst] = cv.h;
  }
}

// ---------------- fused LN + QKV GEMM (MFMA), register LN, no LDS ----------------
__global__ __launch_bounds__(256, 4)
void k_qkv(const float* __restrict__ x, const float* __restrict__ ln_w,
           const float* __restrict__ ln_b, const u16* __restrict__ Wqkvs,
           const float* __restrict__ bq, const float* __restrict__ bk,
           const float* __restrict__ bv,
           u16* __restrict__ qo, u16* __restrict__ ko, u16* __restrict__ vo) {
  const int tid = threadIdx.x;
  const int row0 = blockIdx.x * 64;
  const int lane = tid & 63, wv = tid >> 6;
  const int l15 = lane & 15, quad = lane >> 4;
  const int m0 = wv * 16;

  bf16x8 af[4];
  reg_ln(x + (size_t)(row0 + m0 + l15) * Dx + quad * 8, ln_w, ln_b, quad, af);

  int bl[4], ll[4];
  #pragma unroll
  for (int r = 0; r < 4; ++r) {
    int gr = row0 + m0 + quad * 4 + r;
    bl[r] = gr / 200;
    ll[r] = gr - bl[r] * 200;
  }

  const float scale = 0.17677669529663687f;
  #pragma unroll
  for (int nt = 0; nt < 24; ++nt) {
    f32x4 acc = (f32x4){0.f, 0.f, 0.f, 0.f};
    const u16* wb = Wqkvs + ((size_t)(nt * 4) * 64 + lane) * 8;
    #pragma unroll
    for (int kst = 0; kst < 4; ++kst) {
      bf16x8 bfr = *(const bf16x8*)(wb + kst * 64 * 8);
      acc = __builtin_amdgcn_mfma_f32_16x16x32_bf16(af[kst], bfr, acc, 0, 0, 0);
    }
    const int col = (nt & 7) * 16 + l15;
    const int head = col >> 5, dk = col & 31;
    if (nt < 8) {
      float bb = bq[col];
      #pragma unroll
      for (int r = 0; r < 4; ++r)
        qo[((size_t)(bl[r] * 4 + head) * 200 + ll[r]) * 32 + dk] = f2bf((acc[r] + bb) * scale);
    } else if (nt < 16) {
      float bb = bk[col];
      #pragma unroll
      for (int r = 0; r < 4; ++r)
        ko[((size_t)(bl[r] * 4 + head) * 200 + ll[r]) * 32 + dk] = f2bf(acc[r] + bb);
    } else {
      float bb = bv[col];
      #pragma unroll
      for (int r = 0; r < 4; ++r)
        vo[((size_t)(bl[r] * 4 + head) * 200 + ll[r]) * 32 + dk] = f2bf(acc[r] + bb);
    }
  }
}

// ---------------- MFMA attention: TWO blocks per (b_local, head) ----------------
// half=blockIdx&1 splits the 13 m-tiles into 7 (0-6) + 6 (7-12): max 2 mt-iters
// per wave (was 4 -> 25% tail idle), and 2x block-level parallelism for latency
// hiding. V is staged per half-block (L2-hot, cheap).
__global__ __launch_bounds__(256, 3)
void k_attn2(const u16* __restrict__ q, const u16* __restrict__ k,
             const u16* __restrict__ v, const int* __restrict__ seq,
             u16* __restrict__ attn) {
  __shared__ float smask[224];
  __shared__ __align__(16) u16 vt[32 * PVP];
  __shared__ __align__(16) u16 Pb[4][16 * PVP];
  const int tid = threadIdx.x;
  const int bl = blockIdx.x >> 3, head = (blockIdx.x >> 1) & 3;
  const int bh = blockIdx.x >> 1;
  const int half = blockIdx.x & 1;
  const int lane = tid & 63, wv = tid >> 6;
  const int l15 = lane & 15, quad = lane >> 4;

  if (tid < 224)
    smask[tid] = (tid < 200 && seq[bl * 200 + tid] > 0) ? 0.f : -1e9f;
  // stage V^T into LDS: vt[dk][l]
  #pragma unroll 1
  for (int e = tid; e < 800; e += 256) {
    int l = e >> 2, g = (e & 3) * 8;
    uint4 pv = *(const uint4*)(v + ((size_t)bh * 200 + l) * 32 + g);
    const u16* pw = (const u16*)&pv;
    #pragma unroll
    for (int j = 0; j < 8; ++j) vt[(g + j) * PVP + l] = pw[j];
  }
  // zero V^T pad cols [200,232)
  #pragma unroll 1
  for (int e = tid; e < 1024; e += 256) {
    int rr = e >> 5, cc = 200 + (e & 31);
    vt[rr * PVP + cc] = 0;
  }
  __syncthreads();

  float msk[14];
  #pragma unroll
  for (int nt = 0; nt < 14; ++nt) msk[nt] = smask[nt * 16 + l15];

  const u16* qbase = q + (size_t)bh * 200 * 32;
  const u16* kbase = k + (size_t)bh * 200 * 32;
  u16* Pw = Pb[wv];

  const int mt0 = half ? 7 : 0;
  const int mte = half ? 13 : 7;
  #pragma unroll 1
  for (int mt = mt0 + wv; mt < mte; mt += 4) {
    bf16x8 qf = *(const bf16x8*)(qbase + (mt * 16 + l15) * 32 + quad * 8);
    f32x4 s[14];
    #pragma unroll
    for (int nt = 0; nt < 14; ++nt) {
      bf16x8 kf = *(const bf16x8*)(kbase + (nt * 16 + l15) * 32 + quad * 8);
      s[nt] = __builtin_amdgcn_mfma_f32_16x16x32_bf16(qf, kf, (f32x4){0.f, 0.f, 0.f, 0.f}, 0, 0, 0);
    }
    // mask + row max
    float rmax[4] = {-1e30f, -1e30f, -1e30f, -1e30f};
    #pragma unroll
    for (int nt = 0; nt < 14; ++nt) {
      #pragma unroll
      for (int r = 0; r < 4; ++r) {
        s[nt][r] += msk[nt];
        rmax[r] = fmaxf(rmax[r], s[nt][r]);
      }
    }
    #pragma unroll
    for (int m = 1; m < 16; m <<= 1) {
      #pragma unroll
      for (int r = 0; r < 4; ++r) rmax[r] = fmaxf(rmax[r], __shfl_xor(rmax[r], m));
    }
    // exp + row sum
    float rsum[4] = {0.f, 0.f, 0.f, 0.f};
    #pragma unroll
    for (int nt = 0; nt < 14; ++nt) {
      #pragma unroll
      for (int r = 0; r < 4; ++r) {
        float p = __expf(s[nt][r] - rmax[r]);
        s[nt][r] = p;
        rsum[r] += p;
      }
    }
    #pragma unroll
    for (int m = 1; m < 16; m <<= 1) {
      #pragma unroll
      for (int r = 0; r < 4; ++r) rsum[r] += __shfl_xor(rsum[r], m);
    }
    float inv[4];
    #pragma unroll
    for (int r = 0; r < 4; ++r) inv[r] = 1.0f / rsum[r];
    // P -> wave-private LDS (bf16, unnormalized)
    #pragma unroll
    for (int nt = 0; nt < 14; ++nt) {
      #pragma unroll
      for (int r = 0; r < 4; ++r)
        Pw[(quad * 4 + r) * PVP + nt * 16 + l15] = f2bf(s[nt][r]);
    }
    __asm__ __volatile__("s_waitcnt lgkmcnt(0)" ::: "memory");
    // O = P @ V
    f32x4 o0 = (f32x4){0.f, 0.f, 0.f, 0.f}, o1 = (f32x4){0.f, 0.f, 0.f, 0.f};
    #pragma unroll
    for (int kst = 0; kst < 7; ++kst) {
      bf16x8 pf  = *(const bf16x8*)&Pw[l15 * PVP + kst * 32 + quad * 8];
      bf16x8 vf0 = *(const bf16x8*)&vt[l15 * PVP + kst * 32 + quad * 8];
      bf16x8 vf1 = *(const bf16x8*)&vt[(16 + l15) * PVP + kst * 32 + quad * 8];
      o0 = __builtin_amdgcn_mfma_f32_16x16x32_bf16(pf, vf0, o0, 0, 0, 0);
      o1 = __builtin_amdgcn_mfma_f32_16x16x32_bf16(pf, vf1, o1, 0, 0, 0);
    }
    #pragma unroll
    for (int r = 0; r < 4; ++r) {
      int row = mt * 16 + quad * 4 + r;
      if (row < 200) {
        u16* op = attn + ((size_t)bl * 200 + row) * 128 + head * 32;
        op[l15]      = f2bf(o0[r] * inv[r]);
        op[16 + l15] = f2bf(o1[r] * inv[r]);
      }
    }
  }
}

// ---------------- O-projection + residual (MFMA): x += a @ Wo + bo ----------------
__global__ __launch_bounds__(256, 4)
void k_oproj(const u16* __restrict__ a, const u16* __restrict__ Wos,
             const float* __restrict__ bo, float* __restrict__ x) {
  const int tid = threadIdx.x;
  const int lane = tid & 63, wv = tid >> 6;
  const int l15 = lane & 15, quad = lane >> 4;
  const size_t m0 = (size_t)blockIdx.x * 64 + wv * 16;
  f32x4 acc[8];
  #pragma unroll
  for (int i = 0; i < 8; ++i) acc[i] = (f32x4){0.f, 0.f, 0.f, 0.f};
  #pragma unroll
  for (int kst = 0; kst < 4; ++kst) {
    bf16x8 af = *(const bf16x8*)(a + (m0 + l15) * Dx + kst * 32 + quad * 8);
    const u16* wb = Wos + (kst * 64 + lane) * 8;
    #pragma unroll
    for (int nt = 0; nt < 8; ++nt) {
      bf16x8 bf = *(const bf16x8*)(wb + nt * (4 * 64 * 8));
      acc[nt] = __builtin_amdgcn_mfma_f32_16x16x32_bf16(af, bf, acc[nt], 0, 0, 0);
    }
  }
  #pragma unroll
  for (int nt = 0; nt < 8; ++nt) {
    int col = nt * 16 + l15;
    float bb = bo[col];
    #pragma unroll
    for (int r = 0; r < 4; ++r) {
      size_t idx = (m0 + quad * 4 + r) * Dx + col;
      x[idx] += acc[nt][r] + bb;
    }
  }
}

// ---------------- fused LN + FFN (MFMA): x += gelu(LN(x)@W1+b1)@W2 + b2 ----------------
// 512 threads / 8 waves / 128 rows. Register LN (no hs LDS, no LN barrier).
// Weights staged per-kst (8 KB) double-buffered with ASYNC SPLIT: global load issued
// at phase start (reg), ds_write after the MFMA loop -> HBM/L2 latency hides under
// compute, barrier drain is short, and MFMA's ds_reads don't queue behind staging in
// the in-order lgkm counter. GELU fused per GEMM2-kst through a 32-col wave-private
// ts slice. LDS 42 KB static. (Exact round-4 version, measured 152 us.)
__global__ __launch_bounds__(512, 4)
void k_ffn(float* __restrict__ x, const float* __restrict__ ln_w,
           const float* __restrict__ ln_b,
           const u16* __restrict__ W1s, const float* __restrict__ b1,
           const u16* __restrict__ W2s, const float* __restrict__ b2) {
  __shared__ __align__(16) u16 smem[5120 + 8192 + 8192];
  u16* ts  = smem;            // [128][TSP=40]
  u16* w1b = smem + 5120;     // 2 x 4096 u16 (8 KB each)
  u16* w2b = smem + 13312;    // 2 x 4096 u16
  const int tid = threadIdx.x;
  const size_t row0 = (size_t)blockIdx.x * 128;
  const int lane = tid & 63, wv = tid >> 6;           // wv in [0,8)
  const int l15 = lane & 15, quad = lane >> 4;
  const int m0 = wv * 16;
  const int snt = wv, soff = lane;                    // staging coords: 8 pieces x 1KB

  bf16x8 af[4];
  reg_ln(x + (row0 + m0 + l15) * (size_t)Dx + quad * 8, ln_w, ln_b, quad, af);

  // prologue: stage W1(ch0,kst0) and W2(ch0,p0)
  ((uint4*)w1b)[tid] = ((const uint4*)(W1s + (size_t)(snt * 4) * 512))[soff];
  ((uint4*)w2b)[tid] = ((const uint4*)(W2s + (size_t)(snt * 16) * 512))[soff];
  __syncthreads();

  f32x4 acc2[8];
  #pragma unroll
  for (int i = 0; i < 8; ++i) acc2[i] = (f32x4){0.f, 0.f, 0.f, 0.f};

  #pragma unroll 1
  for (int ch = 0; ch < 4; ++ch) {
    // ---- GEMM1: 4 kst phases, dbuf, async-split staging ----
    f32x4 acc1[8];
    #pragma unroll
    for (int i = 0; i < 8; ++i) acc1[i] = (f32x4){0.f, 0.f, 0.f, 0.f};
    #pragma unroll
    for (int kst = 0; kst < 4; ++kst) {
      uint4 stg;
      if (kst < 3)
        stg = ((const uint4*)(W1s + (size_t)((ch * 8 + snt) * 4 + kst + 1) * 512))[soff];
      const u16* wb = w1b + (kst & 1) * 4096;
      #pragma unroll
      for (int nt = 0; nt < 8; ++nt) {
        bf16x8 bfr = *(const bf16x8*)&wb[nt * 512 + lane * 8];
        acc1[nt] = __builtin_amdgcn_mfma_f32_16x16x32_bf16(af[kst], bfr, acc1[nt], 0, 0, 0);
      }
      if (kst < 3)
        ((uint4*)(w1b + ((kst + 1) & 1) * 4096))[tid] = stg;
      __syncthreads();
    }
    // ---- GELU + GEMM2: 4 kst phases; slice p of gelu feeds kst p ----
    #pragma unroll
    for (int p = 0; p < 4; ++p) {
      uint4 stg2, stg1;
      const bool s2  = (p < 3);
      const bool s1n = (p == 3) && (ch < 3);
      if (s2)
        stg2 = ((const uint4*)(W2s + (size_t)(snt * 16 + ch * 4 + p + 1) * 512))[soff];
      if (s1n) {
        stg1 = ((const uint4*)(W1s + (size_t)((ch + 1) * 8 + snt) * 4 * 512))[soff];
        stg2 = ((const uint4*)(W2s + (size_t)(snt * 16 + (ch + 1) * 4) * 512))[soff];
      }
      // GELU slice p (cols p*32..p*32+32 of this ch) -> ts, wave-private rows
      #pragma unroll
      for (int q2 = 0; q2 < 2; ++q2) {
        const int ntg = 2 * p + q2;
        float bb = b1[ch * 128 + ntg * 16 + l15];
        #pragma unroll
        for (int r = 0; r < 4; ++r)
          ts[(m0 + quad * 4 + r) * TSP + q2 * 16 + l15] =
              f2bf(gelu_f(acc1[ntg][r] + bb));
      }
      __asm__ __volatile__("s_waitcnt lgkmcnt(0)" ::: "memory");
      bf16x8 tf = *(const bf16x8*)&ts[(m0 + l15) * TSP + quad * 8];
      const u16* wb = w2b + (p & 1) * 4096;
      #pragma unroll
      for (int nt = 0; nt < 8; ++nt) {
        bf16x8 bfr = *(const bf16x8*)&wb[nt * 512 + lane * 8];
        acc2[nt] = __builtin_amdgcn_mfma_f32_16x16x32_bf16(tf, bfr, acc2[nt], 0, 0, 0);
      }
      if (s2)
        ((uint4*)(w2b + ((p + 1) & 1) * 4096))[tid] = stg2;
      if (s1n) {
        ((uint4*)w1b)[tid] = stg1;
        ((uint4*)w2b)[tid] = stg2;
      }
      __syncthreads();
    }
  }
  #pragma unroll
  for (int nt = 0; nt < 8; ++nt) {
    int col = nt * 16 + l15;
    float bb = b2[col];
    #pragma unroll
    for (int r = 0; r < 4; ++r) {
      size_t idx = (row0 + m0 + quad * 4 + r) * Dx + col;
      x[idx] += acc2[nt][r] + bb;
    }
  }
}

// ---------------- final FC (MFMA, split-K 32) ----------------
__global__ __launch_bounds__(256, 4)
void k_fc(const float* __restrict__ x, const u16* __restrict__ fcWs,
          float* __restrict__ part) {
  const int tid = threadIdx.x;
  const int lane = tid & 63, wv = tid >> 6;
  const int l15 = lane & 15, quad = lane >> 4;
  const int m0 = blockIdx.x * 64 + wv * 16;
  const int ky = blockIdx.y;
  f32x4 acc[8];
  #pragma unroll
  for (int i = 0; i < 8; ++i) acc[i] = (f32x4){0.f, 0.f, 0.f, 0.f};
  const float* xp = x + (size_t)(m0 + l15) * 25600 + quad * 8;
  #pragma unroll 1
  for (int kst = ky * 25; kst < ky * 25 + 25; ++kst) {
    float4 xa = *(const float4*)(xp + kst * 32);
    float4 xb2 = *(const float4*)(xp + kst * 32 + 4);
    bf16x8 af;
    af[0] = (short)f2bf(xa.x);  af[1] = (short)f2bf(xa.y);
    af[2] = (short)f2bf(xa.z);  af[3] = (short)f2bf(xa.w);
    af[4] = (short)f2bf(xb2.x); af[5] = (short)f2bf(xb2.y);
    af[6] = (short)f2bf(xb2.z); af[7] = (short)f2bf(xb2.w);
    const u16* wb = fcWs + ((size_t)kst * 64 + lane) * 8;
    #pragma unroll
    for (int nt = 0; nt < 8; ++nt) {
      bf16x8 bf = *(const bf16x8*)(wb + (size_t)nt * (800 * 64 * 8));
      acc[nt] = __builtin_amdgcn_mfma_f32_16x16x32_bf16(af, bf, acc[nt], 0, 0, 0);
    }
  }
  float* pp = part + (size_t)ky * (Bx * Dx);
  #pragma unroll
  for (int nt = 0; nt < 8; ++nt) {
    #pragma unroll
    for (int r = 0; r < 4; ++r) {
      pp[(size_t)(m0 + quad * 4 + r) * Dx + nt * 16 + l15] = acc[nt][r];
    }
  }
}

__global__ void k_fcred(const float* __restrict__ part, const float* __restrict__ fcb,
                        float* __restrict__ out) {
  int i = blockIdx.x * 256 + threadIdx.x;
  float s = fcb[i & 127];
  #pragma unroll
  for (int k = 0; k < 32; ++k) s += part[(size_t)k * (Bx * Dx) + i];
  out[i] = s;
}

extern "C" void kernel_launch(void* const* d_in, const int* in_sizes, int n_in,
                              void* d_out, int out_size, void* d_ws, size_t ws_size,
                              hipStream_t stream) {
  const int*   seq  = (const int*)d_in[0];
  const float* tok  = (const float*)d_in[1];
  const float* pos  = (const float*)d_in[2];
  const float* Wq   = (const float*)d_in[3];
  const float* bq   = (const float*)d_in[4];
  const float* Wk   = (const float*)d_in[5];
  const float* bk   = (const float*)d_in[6];
  const float* Wv   = (const float*)d_in[7];
  const float* bv   = (const float*)d_in[8];
  const float* Wo   = (const float*)d_in[9];
  const float* bo   = (const float*)d_in[10];
  const float* ln1w = (const float*)d_in[11];
  const float* ln1b = (const float*)d_in[12];
  const float* ln2w = (const float*)d_in[13];
  const float* ln2b = (const float*)d_in[14];
  const float* W1   = (const float*)d_in[15];
  const float* b1   = (const float*)d_in[16];
  const float* W2   = (const float*)d_in[17];
  const float* b2   = (const float*)d_in[18];
  const float* fcW  = (const float*)d_in[19];
  const float* fcb  = (const float*)d_in[20];
  float* out = (float*)d_out;

  char* ws = (char*)d_ws;
  const size_t XB = (size_t)Mx * Dx * 4;        // 104,857,600 B
  const size_t WBSZ = 7340032;                  // converted-weight region

  // adaptive batch chunking: 4 equal bf16 regions of (Bx/nc)*51200 B after x
  int nc = 4;
  for (int t = 1; t <= 4; t <<= 1) {
    size_t qsz = (size_t)(Bx / t) * 51200;
    if (XB + 4 * qsz + WBSZ <= ws_size) { nc = t; break; }
  }
  const int BC = Bx / nc;                        // batches per chunk
  const size_t qsz = (size_t)BC * 51200;

  float* x    = (float*)ws;
  u16* qb     = (u16*)(ws + XB);
  u16* kb     = (u16*)(ws + XB + qsz);
  u16* vb     = (u16*)(ws + XB + 2 * qsz);
  u16* ab     = (u16*)(ws + XB + 3 * qsz);
  float* part = (float*)(ws + XB);               // aliases q/k (dead by k_fc)
  char* WB    = ws + XB + 4 * qsz;
  u16* W1s0   = (u16*)(WB);
  u16* W1s1   = (u16*)(WB + 131072);
  u16* W2s0   = (u16*)(WB + 262144);
  u16* W2s1   = (u16*)(WB + 393216);
  u16* Wos0   = (u16*)(WB + 524288);
  u16* Wos1   = (u16*)(WB + 557056);
  u16* Wqkvs0 = (u16*)(WB + 589824);
  u16* Wqkvs1 = (u16*)(WB + 688128);
  u16* fcWs   = (u16*)(WB + 786432);

  // ---- merged weight conversion: ONE launch for all 13 tensors ----
  CvtJobs J;
  const float* srcs[13] = {W1, W1 + Dx * FFx, W2, W2 + FFx * Dx,
                           Wo, Wo + Dx * Dx,
                           Wq, Wk, Wv,
                           Wq + Dx * Dx, Wk + Dx * Dx, Wv + Dx * Dx,
                           fcW};
  u16* dsts[13] = {W1s0, W1s1, W2s0, W2s1, Wos0, Wos1,
                   Wqkvs0, Wqkvs0 + 16384, Wqkvs0 + 32768,
                   Wqkvs1, Wqkvs1 + 16384, Wqkvs1 + 32768,
                   fcWs};
  const int Ns[13]  = {FFx, FFx, Dx, Dx, Dx, Dx, Dx, Dx, Dx, Dx, Dx, Dx, Dx};
  const int kss[13] = {4, 4, 16, 16, 4, 4, 4, 4, 4, 4, 4, 4, 800};
  const int nblk[13] = {32, 32, 32, 32, 8, 8, 8, 8, 8, 8, 8, 8, 1600};
  int acc = 0;
  for (int j = 0; j < 13; ++j) {
    J.src[j] = srcs[j]; J.dst[j] = dsts[j]; J.N[j] = Ns[j]; J.ks[j] = kss[j];
    J.bstart[j] = acc; acc += nblk[j];
  }
  J.bstart[13] = acc;   // 1792
  k_cvt_all<<<acc, 256, 0, stream>>>(J);

  k_embed<<<25600, 256, 0, stream>>>(seq, tok, pos, x);
  const int cblk = BC * 200 / 64;   // 64-row blocks per chunk
  for (int i = 0; i < 2; ++i) {
    const u16* Wqkvs = (i == 0) ? Wqkvs0 : Wqkvs1;
    const u16* Wos   = (i == 0) ? Wos0 : Wos1;
    for (int c = 0; c < nc; ++c) {
      float* xc = x + (size_t)c * BC * 200 * 128;
      const int* seqc = seq + (size_t)c * BC * 200;
      k_qkv<<<cblk, 256, 0, stream>>>(xc, ln1w + i * Dx, ln1b + i * Dx, Wqkvs,
                                      bq + i * Dx, bk + i * Dx, bv + i * Dx,
                                      qb, kb, vb);
      k_attn2<<<BC * 8, 256, 0, stream>>>(qb, kb, vb, seqc, ab);
      k_oproj<<<cblk, 256, 0, stream>>>(ab, Wos, bo + i * Dx, xc);
    }
    k_ffn<<<1600, 512, 0, stream>>>(x, ln2w + i * Dx, ln2b + i * Dx,
                                    (i == 0) ? W1s0 : W1s1, b1 + i * FFx,
                                    (i == 0) ? W2s0 : W2s1, b2 + i * Dx);
  }
  k_fc<<<dim3(16, 32), 256, 0, stream>>>(x, fcWs, part);
  k_fcred<<<512, 256, 0, stream>>>(part, fcb, out);
}

// Round 7
// 917.867 us; speedup vs baseline: 1.1287x; 1.0774x over previous
//
#include <hip/hip_runtime.h>
#include <math.h>

typedef unsigned short u16;
typedef unsigned int u32;
typedef __attribute__((ext_vector_type(8))) short bf16x8;
typedef __attribute__((ext_vector_type(4))) float f32x4;

#define Bx 1024
#define Lx 200
#define Dx 128
#define FFx 512
#define Mx (Bx*Lx)
#define PVP 232   // P/V^T LDS row stride (u16)
#define TSP 40    // ts row stride (u16): 32 cols + 8 pad; 2-way pattern (free)

__device__ __forceinline__ u16 f2bf(float f) {
  u32 u = __float_as_uint(f);
  u32 r = (u + 0x7fffu + ((u >> 16) & 1u)) >> 16;
  return (u16)r;
}

// fast GELU: tanh form, v*sigmoid(1.59577v + 0.0713548 v^3).
// |err| vs exact erf-gelu < 1e-4 for |v|<2 (pre-act sigma~0.23) — below bf16 eps.
__device__ __forceinline__ float gelu_f(float v) {
  float z = v * fmaf(v * v, 0.0713548163f, 1.5957691216f);
  float e = __expf(-z);
  return v * __builtin_amdgcn_rcpf(1.0f + e);
}

union BFCV { u32 u[4]; bf16x8 h; };

// ---------------- merged weight convert: fp32 [K][N] -> bf16 fragment order -------
// One launch for all 13 weight tensors. dst: [n_tile][k_step][lane][8],
// val = src[kst*32 + (lane>>4)*8 + j][ntile*16 + (lane&15)]
struct CvtJobs {
  const float* src[13];
  u16* dst[13];
  int N[13];
  int ks[13];
  int bstart[14];
};

__global__ void k_cvt_all(CvtJobs J) {
  const int b = blockIdx.x;
  int j = 0;
  #pragma unroll 1
  while (b >= J.bstart[j + 1]) ++j;          // uniform per block (scalar)
  const float* __restrict__ src = J.src[j];
  u16* __restrict__ dst = J.dst[j];
  const int N = J.N[j], k_steps = J.ks[j];
  int id = (b - J.bstart[j]) * 256 + threadIdx.x;
  int lane = id & 63;
  int rest = id >> 6;
  int kst = rest % k_steps;
  int ntile = rest / k_steps;
  int n = ntile * 16 + (lane & 15);
  int kb = kst * 32 + ((lane >> 4) << 3);
  const float* sp = src + (size_t)kb * N + n;
  u32 w[4];
  #pragma unroll
  for (int jj = 0; jj < 4; ++jj) {
    u32 lo = f2bf(sp[(size_t)(2 * jj) * N]);
    u32 hi = f2bf(sp[(size_t)(2 * jj + 1) * N]);
    w[jj] = lo | (hi << 16);
  }
  ((uint4*)dst)[id] = make_uint4(w[0], w[1], w[2], w[3]);
}

// ---------------- embedding: x = tok[seq] + pos ----------------
__global__ void k_embed(const int* __restrict__ seq, const float* __restrict__ tok,
                        const float* __restrict__ pos, float* __restrict__ x) {
  const int i = blockIdx.x * 256 + threadIdx.x;
  const int row = i >> 5, c = i & 31;
  const int t = seq[row];
  const int l = row % Lx;
  const float4 a = ((const float4*)tok)[(size_t)t * 32 + c];
  const float4 p = ((const float4*)pos)[l * 32 + c];
  ((float4*)x)[i] = make_float4(a.x + p.x, a.y + p.y, a.z + p.z, a.w + p.w);
}

// ---- register layernorm: lane (quad,l15) owns row m0+l15, cols kst*32+quad*8..+8.
// Row stats reduced across the 4 quad-lanes via shfl_xor(16/32). Returns af[] A-frags.
__device__ __forceinline__ void reg_ln(const float* __restrict__ xr,
                                       const float* __restrict__ ln_w,
                                       const float* __restrict__ ln_b,
                                       int quad, bf16x8 af[4]) {
  float v[32];
  float s = 0.f, sq = 0.f;
  #pragma unroll
  for (int kst = 0; kst < 4; ++kst) {
    float4 a = *(const float4*)(xr + kst * 32);
    float4 b = *(const float4*)(xr + kst * 32 + 4);
    v[kst * 8 + 0] = a.x; v[kst * 8 + 1] = a.y; v[kst * 8 + 2] = a.z; v[kst * 8 + 3] = a.w;
    v[kst * 8 + 4] = b.x; v[kst * 8 + 5] = b.y; v[kst * 8 + 6] = b.z; v[kst * 8 + 7] = b.w;
  }
  #pragma unroll
  for (int i = 0; i < 32; ++i) { s += v[i]; sq = fmaf(v[i], v[i], sq); }
  s  += __shfl_xor(s, 16);  s  += __shfl_xor(s, 32);
  sq += __shfl_xor(sq, 16); sq += __shfl_xor(sq, 32);
  float mu = s * 0.0078125f;
  float rr = rsqrtf(fmaf(-mu, mu, sq * 0.0078125f) + 1e-5f);
  #pragma unroll
  for (int kst = 0; kst < 4; ++kst) {
    const float* lwp = ln_w + kst * 32 + quad * 8;
    const float* lbp = ln_b + kst * 32 + quad * 8;
    float4 lw0 = *(const float4*)(lwp);
    float4 lw1 = *(const float4*)(lwp + 4);
    float4 lb0 = *(const float4*)(lbp);
    float4 lb1 = *(const float4*)(lbp + 4);
    float hw[8] = {lw0.x, lw0.y, lw0.z, lw0.w, lw1.x, lw1.y, lw1.z, lw1.w};
    float hb[8] = {lb0.x, lb0.y, lb0.z, lb0.w, lb1.x, lb1.y, lb1.z, lb1.w};
    BFCV cv;
    #pragma unroll
    for (int j = 0; j < 4; ++j) {
      float h0 = fmaf((v[kst * 8 + 2 * j]     - mu) * rr, hw[2 * j],     hb[2 * j]);
      float h1 = fmaf((v[kst * 8 + 2 * j + 1] - mu) * rr, hw[2 * j + 1], hb[2 * j + 1]);
      cv.u[j] = (u32)f2bf(h0) | ((u32)f2bf(h1) << 16);
    }
    af[kst] = cv.h;
  }
}

// ---------------- fused LN + QKV GEMM (MFMA), register LN, no LDS ----------------
__global__ __launch_bounds__(256, 4)
void k_qkv(const float* __restrict__ x, const float* __restrict__ ln_w,
           const float* __restrict__ ln_b, const u16* __restrict__ Wqkvs,
           const float* __restrict__ bq, const float* __restrict__ bk,
           const float* __restrict__ bv,
           u16* __restrict__ qo, u16* __restrict__ ko, u16* __restrict__ vo) {
  const int tid = threadIdx.x;
  const int row0 = blockIdx.x * 64;
  const int lane = tid & 63, wv = tid >> 6;
  const int l15 = lane & 15, quad = lane >> 4;
  const int m0 = wv * 16;

  bf16x8 af[4];
  reg_ln(x + (size_t)(row0 + m0 + l15) * Dx + quad * 8, ln_w, ln_b, quad, af);

  int bl[4], ll[4];
  #pragma unroll
  for (int r = 0; r < 4; ++r) {
    int gr = row0 + m0 + quad * 4 + r;
    bl[r] = gr / 200;
    ll[r] = gr - bl[r] * 200;
  }

  const float scale = 0.17677669529663687f;
  #pragma unroll
  for (int nt = 0; nt < 24; ++nt) {
    f32x4 acc = (f32x4){0.f, 0.f, 0.f, 0.f};
    const u16* wb = Wqkvs + ((size_t)(nt * 4) * 64 + lane) * 8;
    #pragma unroll
    for (int kst = 0; kst < 4; ++kst) {
      bf16x8 bfr = *(const bf16x8*)(wb + kst * 64 * 8);
      acc = __builtin_amdgcn_mfma_f32_16x16x32_bf16(af[kst], bfr, acc, 0, 0, 0);
    }
    const int col = (nt & 7) * 16 + l15;
    const int head = col >> 5, dk = col & 31;
    if (nt < 8) {
      float bb = bq[col];
      #pragma unroll
      for (int r = 0; r < 4; ++r)
        qo[((size_t)(bl[r] * 4 + head) * 200 + ll[r]) * 32 + dk] = f2bf((acc[r] + bb) * scale);
    } else if (nt < 16) {
      float bb = bk[col];
      #pragma unroll
      for (int r = 0; r < 4; ++r)
        ko[((size_t)(bl[r] * 4 + head) * 200 + ll[r]) * 32 + dk] = f2bf(acc[r] + bb);
    } else {
      float bb = bv[col];
      #pragma unroll
      for (int r = 0; r < 4; ++r)
        vo[((size_t)(bl[r] * 4 + head) * 200 + ll[r]) * 32 + dk] = f2bf(acc[r] + bb);
    }
  }
}

// ---------------- MFMA attention: one block per (b_local, head) ----------------
// (round-4 version: the round-6 half-split cost more in duplicated V/K traffic
// than its tail-balance gain)
__global__ __launch_bounds__(256, 3)
void k_attn2(const u16* __restrict__ q, const u16* __restrict__ k,
             const u16* __restrict__ v, const int* __restrict__ seq,
             u16* __restrict__ attn) {
  __shared__ float smask[224];
  __shared__ __align__(16) u16 vt[32 * PVP];
  __shared__ __align__(16) u16 Pb[4][16 * PVP];
  const int tid = threadIdx.x;
  const int bl = blockIdx.x >> 2, head = blockIdx.x & 3;
  const int bh = blockIdx.x;
  const int lane = tid & 63, wv = tid >> 6;
  const int l15 = lane & 15, quad = lane >> 4;

  if (tid < 224)
    smask[tid] = (tid < 200 && seq[bl * 200 + tid] > 0) ? 0.f : -1e9f;
  // stage V^T into LDS: vt[dk][l]
  #pragma unroll 1
  for (int e = tid; e < 800; e += 256) {
    int l = e >> 2, g = (e & 3) * 8;
    uint4 pv = *(const uint4*)(v + ((size_t)bh * 200 + l) * 32 + g);
    const u16* pw = (const u16*)&pv;
    #pragma unroll
    for (int j = 0; j < 8; ++j) vt[(g + j) * PVP + l] = pw[j];
  }
  // zero V^T pad cols [200,232)
  #pragma unroll 1
  for (int e = tid; e < 1024; e += 256) {
    int rr = e >> 5, cc = 200 + (e & 31);
    vt[rr * PVP + cc] = 0;
  }
  __syncthreads();

  float msk[14];
  #pragma unroll
  for (int nt = 0; nt < 14; ++nt) msk[nt] = smask[nt * 16 + l15];

  const u16* qbase = q + (size_t)bh * 200 * 32;
  const u16* kbase = k + (size_t)bh * 200 * 32;
  u16* Pw = Pb[wv];

  #pragma unroll 1
  for (int mt = wv; mt < 13; mt += 4) {
    bf16x8 qf = *(const bf16x8*)(qbase + (mt * 16 + l15) * 32 + quad * 8);
    f32x4 s[14];
    #pragma unroll
    for (int nt = 0; nt < 14; ++nt) {
      bf16x8 kf = *(const bf16x8*)(kbase + (nt * 16 + l15) * 32 + quad * 8);
      s[nt] = __builtin_amdgcn_mfma_f32_16x16x32_bf16(qf, kf, (f32x4){0.f, 0.f, 0.f, 0.f}, 0, 0, 0);
    }
    // mask + row max
    float rmax[4] = {-1e30f, -1e30f, -1e30f, -1e30f};
    #pragma unroll
    for (int nt = 0; nt < 14; ++nt) {
      #pragma unroll
      for (int r = 0; r < 4; ++r) {
        s[nt][r] += msk[nt];
        rmax[r] = fmaxf(rmax[r], s[nt][r]);
      }
    }
    #pragma unroll
    for (int m = 1; m < 16; m <<= 1) {
      #pragma unroll
      for (int r = 0; r < 4; ++r) rmax[r] = fmaxf(rmax[r], __shfl_xor(rmax[r], m));
    }
    // exp + row sum
    float rsum[4] = {0.f, 0.f, 0.f, 0.f};
    #pragma unroll
    for (int nt = 0; nt < 14; ++nt) {
      #pragma unroll
      for (int r = 0; r < 4; ++r) {
        float p = __expf(s[nt][r] - rmax[r]);
        s[nt][r] = p;
        rsum[r] += p;
      }
    }
    #pragma unroll
    for (int m = 1; m < 16; m <<= 1) {
      #pragma unroll
      for (int r = 0; r < 4; ++r) rsum[r] += __shfl_xor(rsum[r], m);
    }
    float inv[4];
    #pragma unroll
    for (int r = 0; r < 4; ++r) inv[r] = 1.0f / rsum[r];
    // P -> wave-private LDS (bf16, unnormalized)
    #pragma unroll
    for (int nt = 0; nt < 14; ++nt) {
      #pragma unroll
      for (int r = 0; r < 4; ++r)
        Pw[(quad * 4 + r) * PVP + nt * 16 + l15] = f2bf(s[nt][r]);
    }
    __asm__ __volatile__("s_waitcnt lgkmcnt(0)" ::: "memory");
    // O = P @ V
    f32x4 o0 = (f32x4){0.f, 0.f, 0.f, 0.f}, o1 = (f32x4){0.f, 0.f, 0.f, 0.f};
    #pragma unroll
    for (int kst = 0; kst < 7; ++kst) {
      bf16x8 pf  = *(const bf16x8*)&Pw[l15 * PVP + kst * 32 + quad * 8];
      bf16x8 vf0 = *(const bf16x8*)&vt[l15 * PVP + kst * 32 + quad * 8];
      bf16x8 vf1 = *(const bf16x8*)&vt[(16 + l15) * PVP + kst * 32 + quad * 8];
      o0 = __builtin_amdgcn_mfma_f32_16x16x32_bf16(pf, vf0, o0, 0, 0, 0);
      o1 = __builtin_amdgcn_mfma_f32_16x16x32_bf16(pf, vf1, o1, 0, 0, 0);
    }
    #pragma unroll
    for (int r = 0; r < 4; ++r) {
      int row = mt * 16 + quad * 4 + r;
      if (row < 200) {
        u16* op = attn + ((size_t)bl * 200 + row) * 128 + head * 32;
        op[l15]      = f2bf(o0[r] * inv[r]);
        op[16 + l15] = f2bf(o1[r] * inv[r]);
      }
    }
  }
}

// ---------------- O-projection + residual (MFMA): x += a @ Wo + bo ----------------
__global__ __launch_bounds__(256, 4)
void k_oproj(const u16* __restrict__ a, const u16* __restrict__ Wos,
             const float* __restrict__ bo, float* __restrict__ x) {
  const int tid = threadIdx.x;
  const int lane = tid & 63, wv = tid >> 6;
  const int l15 = lane & 15, quad = lane >> 4;
  const size_t m0 = (size_t)blockIdx.x * 64 + wv * 16;
  f32x4 acc[8];
  #pragma unroll
  for (int i = 0; i < 8; ++i) acc[i] = (f32x4){0.f, 0.f, 0.f, 0.f};
  #pragma unroll
  for (int kst = 0; kst < 4; ++kst) {
    bf16x8 af = *(const bf16x8*)(a + (m0 + l15) * Dx + kst * 32 + quad * 8);
    const u16* wb = Wos + (kst * 64 + lane) * 8;
    #pragma unroll
    for (int nt = 0; nt < 8; ++nt) {
      bf16x8 bf = *(const bf16x8*)(wb + nt * (4 * 64 * 8));
      acc[nt] = __builtin_amdgcn_mfma_f32_16x16x32_bf16(af, bf, acc[nt], 0, 0, 0);
    }
  }
  #pragma unroll
  for (int nt = 0; nt < 8; ++nt) {
    int col = nt * 16 + l15;
    float bb = bo[col];
    #pragma unroll
    for (int r = 0; r < 4; ++r) {
      size_t idx = (m0 + quad * 4 + r) * Dx + col;
      x[idx] += acc[nt][r] + bb;
    }
  }
}

// ---------------- fused LN + FFN (MFMA): x += gelu(LN(x)@W1+b1)@W2 + b2 ----------------
// 256 threads / 4 waves / 64 rows (3200 blocks). Same per-wave structure as the
// 512-thread version, but: regs (VGPR~60 + 64 acc-AGPR vs unified file) cap the CU
// at 16 waves, and 4 INDEPENDENT 4-wave blocks hide each other's barrier/vmcnt
// stalls far better than 2 barrier-coupled 8-wave blocks (the measured ~36%
// occupancy plateau). LDS 21.5 KB: ts [64][40] + w1/w2 rolling 2x4KB dbufs.
// Async-split staging: global load at phase start, ds_write after MFMAs.
__global__ __launch_bounds__(256, 4)
void k_ffn(float* __restrict__ x, const float* __restrict__ ln_w,
           const float* __restrict__ ln_b,
           const u16* __restrict__ W1s, const float* __restrict__ b1,
           const u16* __restrict__ W2s, const float* __restrict__ b2) {
  __shared__ __align__(16) u16 smem[2560 + 8192 + 8192];
  u16* ts  = smem;            // [64][TSP=40]
  u16* w1b = smem + 2560;     // 2 x 4096 u16 (8 KB each)
  u16* w2b = smem + 10752;    // 2 x 4096 u16
  const int tid = threadIdx.x;
  const size_t row0 = (size_t)blockIdx.x * 64;
  const int lane = tid & 63, wv = tid >> 6;           // wv in [0,4)
  const int l15 = lane & 15, quad = lane >> 4;
  const int m0 = wv * 16;
  const int nt0 = tid >> 6, off = tid & 63;           // staging: 2 x 1KB pieces/thread

  bf16x8 af[4];
  reg_ln(x + (row0 + m0 + l15) * (size_t)Dx + quad * 8, ln_w, ln_b, quad, af);

  // prologue: stage W1(ch0,kst0) and W2(ch0,p0) — 8 KB each, 2 uint4/thread
  ((uint4*)w1b)[tid]       = ((const uint4*)(W1s + (size_t)(nt0 * 4) * 512))[off];
  ((uint4*)w1b)[tid + 256] = ((const uint4*)(W1s + (size_t)((nt0 + 4) * 4) * 512))[off];
  ((uint4*)w2b)[tid]       = ((const uint4*)(W2s + (size_t)(nt0 * 16) * 512))[off];
  ((uint4*)w2b)[tid + 256] = ((const uint4*)(W2s + (size_t)((nt0 + 4) * 16) * 512))[off];
  __syncthreads();

  f32x4 acc2[8];
  #pragma unroll
  for (int i = 0; i < 8; ++i) acc2[i] = (f32x4){0.f, 0.f, 0.f, 0.f};

  #pragma unroll 1
  for (int ch = 0; ch < 4; ++ch) {
    // ---- GEMM1: 4 kst phases, dbuf, async-split staging ----
    f32x4 acc1[8];
    #pragma unroll
    for (int i = 0; i < 8; ++i) acc1[i] = (f32x4){0.f, 0.f, 0.f, 0.f};
    #pragma unroll
    for (int kst = 0; kst < 4; ++kst) {
      uint4 s0, s1;
      if (kst < 3) {
        s0 = ((const uint4*)(W1s + (size_t)((ch * 8 + nt0) * 4 + kst + 1) * 512))[off];
        s1 = ((const uint4*)(W1s + (size_t)((ch * 8 + nt0 + 4) * 4 + kst + 1) * 512))[off];
      }
      const u16* wb = w1b + (kst & 1) * 4096;
      #pragma unroll
      for (int nt = 0; nt < 8; ++nt) {
        bf16x8 bfr = *(const bf16x8*)&wb[nt * 512 + lane * 8];
        acc1[nt] = __builtin_amdgcn_mfma_f32_16x16x32_bf16(af[kst], bfr, acc1[nt], 0, 0, 0);
      }
      if (kst < 3) {
        uint4* d = (uint4*)(w1b + ((kst + 1) & 1) * 4096);
        d[tid] = s0; d[tid + 256] = s1;
      }
      __syncthreads();
    }
    // ---- GELU + GEMM2: 4 p phases; gelu slice p feeds kst p ----
    #pragma unroll
    for (int p = 0; p < 4; ++p) {
      uint4 s0, s1, t0, t1;
      const bool s2  = (p < 3);
      const bool s1n = (p == 3) && (ch < 3);
      if (s2) {
        s0 = ((const uint4*)(W2s + (size_t)(nt0 * 16 + ch * 4 + p + 1) * 512))[off];
        s1 = ((const uint4*)(W2s + (size_t)((nt0 + 4) * 16 + ch * 4 + p + 1) * 512))[off];
      }
      if (s1n) {
        s0 = ((const uint4*)(W1s + (size_t)(((ch + 1) * 8 + nt0) * 4) * 512))[off];
        s1 = ((const uint4*)(W1s + (size_t)(((ch + 1) * 8 + nt0 + 4) * 4) * 512))[off];
        t0 = ((const uint4*)(W2s + (size_t)(nt0 * 16 + (ch + 1) * 4) * 512))[off];
        t1 = ((const uint4*)(W2s + (size_t)((nt0 + 4) * 16 + (ch + 1) * 4) * 512))[off];
      }
      // GELU slice p (cols p*32..p*32+32 of this ch) -> ts, wave-private rows
      #pragma unroll
      for (int q2 = 0; q2 < 2; ++q2) {
        const int ntg = 2 * p + q2;
        float bb = b1[ch * 128 + ntg * 16 + l15];
        #pragma unroll
        for (int r = 0; r < 4; ++r)
          ts[(m0 + quad * 4 + r) * TSP + q2 * 16 + l15] =
              f2bf(gelu_f(acc1[ntg][r] + bb));
      }
      __asm__ __volatile__("s_waitcnt lgkmcnt(0)" ::: "memory");
      bf16x8 tf = *(const bf16x8*)&ts[(m0 + l15) * TSP + quad * 8];
      const u16* wb = w2b + (p & 1) * 4096;
      #pragma unroll
      for (int nt = 0; nt < 8; ++nt) {
        bf16x8 bfr = *(const bf16x8*)&wb[nt * 512 + lane * 8];
        acc2[nt] = __builtin_amdgcn_mfma_f32_16x16x32_bf16(tf, bfr, acc2[nt], 0, 0, 0);
      }
      if (s2) {
        uint4* d = (uint4*)(w2b + ((p + 1) & 1) * 4096);
        d[tid] = s0; d[tid + 256] = s1;
      }
      if (s1n) {
        ((uint4*)w1b)[tid] = s0; ((uint4*)w1b)[tid + 256] = s1;
        ((uint4*)w2b)[tid] = t0; ((uint4*)w2b)[tid + 256] = t1;
      }
      __syncthreads();
    }
  }
  #pragma unroll
  for (int nt = 0; nt < 8; ++nt) {
    int col = nt * 16 + l15;
    float bb = b2[col];
    #pragma unroll
    for (int r = 0; r < 4; ++r) {
      size_t idx = (row0 + m0 + quad * 4 + r) * Dx + col;
      x[idx] += acc2[nt][r] + bb;
    }
  }
}

// ---------------- final FC (MFMA, split-K 32) ----------------
__global__ __launch_bounds__(256, 4)
void k_fc(const float* __restrict__ x, const u16* __restrict__ fcWs,
          float* __restrict__ part) {
  const int tid = threadIdx.x;
  const int lane = tid & 63, wv = tid >> 6;
  const int l15 = lane & 15, quad = lane >> 4;
  const int m0 = blockIdx.x * 64 + wv * 16;
  const int ky = blockIdx.y;
  f32x4 acc[8];
  #pragma unroll
  for (int i = 0; i < 8; ++i) acc[i] = (f32x4){0.f, 0.f, 0.f, 0.f};
  const float* xp = x + (size_t)(m0 + l15) * 25600 + quad * 8;
  #pragma unroll 1
  for (int kst = ky * 25; kst < ky * 25 + 25; ++kst) {
    float4 xa = *(const float4*)(xp + kst * 32);
    float4 xb2 = *(const float4*)(xp + kst * 32 + 4);
    bf16x8 af;
    af[0] = (short)f2bf(xa.x);  af[1] = (short)f2bf(xa.y);
    af[2] = (short)f2bf(xa.z);  af[3] = (short)f2bf(xa.w);
    af[4] = (short)f2bf(xb2.x); af[5] = (short)f2bf(xb2.y);
    af[6] = (short)f2bf(xb2.z); af[7] = (short)f2bf(xb2.w);
    const u16* wb = fcWs + ((size_t)kst * 64 + lane) * 8;
    #pragma unroll
    for (int nt = 0; nt < 8; ++nt) {
      bf16x8 bf = *(const bf16x8*)(wb + (size_t)nt * (800 * 64 * 8));
      acc[nt] = __builtin_amdgcn_mfma_f32_16x16x32_bf16(af, bf, acc[nt], 0, 0, 0);
    }
  }
  float* pp = part + (size_t)ky * (Bx * Dx);
  #pragma unroll
  for (int nt = 0; nt < 8; ++nt) {
    #pragma unroll
    for (int r = 0; r < 4; ++r) {
      pp[(size_t)(m0 + quad * 4 + r) * Dx + nt * 16 + l15] = acc[nt][r];
    }
  }
}

__global__ void k_fcred(const float* __restrict__ part, const float* __restrict__ fcb,
                        float* __restrict__ out) {
  int i = blockIdx.x * 256 + threadIdx.x;
  float s = fcb[i & 127];
  #pragma unroll
  for (int k = 0; k < 32; ++k) s += part[(size_t)k * (Bx * Dx) + i];
  out[i] = s;
}

extern "C" void kernel_launch(void* const* d_in, const int* in_sizes, int n_in,
                              void* d_out, int out_size, void* d_ws, size_t ws_size,
                              hipStream_t stream) {
  const int*   seq  = (const int*)d_in[0];
  const float* tok  = (const float*)d_in[1];
  const float* pos  = (const float*)d_in[2];
  const float* Wq   = (const float*)d_in[3];
  const float* bq   = (const float*)d_in[4];
  const float* Wk   = (const float*)d_in[5];
  const float* bk   = (const float*)d_in[6];
  const float* Wv   = (const float*)d_in[7];
  const float* bv   = (const float*)d_in[8];
  const float* Wo   = (const float*)d_in[9];
  const float* bo   = (const float*)d_in[10];
  const float* ln1w = (const float*)d_in[11];
  const float* ln1b = (const float*)d_in[12];
  const float* ln2w = (const float*)d_in[13];
  const float* ln2b = (const float*)d_in[14];
  const float* W1   = (const float*)d_in[15];
  const float* b1   = (const float*)d_in[16];
  const float* W2   = (const float*)d_in[17];
  const float* b2   = (const float*)d_in[18];
  const float* fcW  = (const float*)d_in[19];
  const float* fcb  = (const float*)d_in[20];
  float* out = (float*)d_out;

  char* ws = (char*)d_ws;
  const size_t XB = (size_t)Mx * Dx * 4;        // 104,857,600 B
  const size_t WBSZ = 7340032;                  // converted-weight region

  // adaptive batch chunking: 4 equal bf16 regions of (Bx/nc)*51200 B after x
  int nc = 4;
  for (int t = 1; t <= 4; t <<= 1) {
    size_t qsz = (size_t)(Bx / t) * 51200;
    if (XB + 4 * qsz + WBSZ <= ws_size) { nc = t; break; }
  }
  const int BC = Bx / nc;                        // batches per chunk
  const size_t qsz = (size_t)BC * 51200;

  float* x    = (float*)ws;
  u16* qb     = (u16*)(ws + XB);
  u16* kb     = (u16*)(ws + XB + qsz);
  u16* vb     = (u16*)(ws + XB + 2 * qsz);
  u16* ab     = (u16*)(ws + XB + 3 * qsz);
  float* part = (float*)(ws + XB);               // aliases q/k (dead by k_fc)
  char* WB    = ws + XB + 4 * qsz;
  u16* W1s0   = (u16*)(WB);
  u16* W1s1   = (u16*)(WB + 131072);
  u16* W2s0   = (u16*)(WB + 262144);
  u16* W2s1   = (u16*)(WB + 393216);
  u16* Wos0   = (u16*)(WB + 524288);
  u16* Wos1   = (u16*)(WB + 557056);
  u16* Wqkvs0 = (u16*)(WB + 589824);
  u16* Wqkvs1 = (u16*)(WB + 688128);
  u16* fcWs   = (u16*)(WB + 786432);

  // ---- merged weight conversion: ONE launch for all 13 tensors ----
  CvtJobs J;
  const float* srcs[13] = {W1, W1 + Dx * FFx, W2, W2 + FFx * Dx,
                           Wo, Wo + Dx * Dx,
                           Wq, Wk, Wv,
                           Wq + Dx * Dx, Wk + Dx * Dx, Wv + Dx * Dx,
                           fcW};
  u16* dsts[13] = {W1s0, W1s1, W2s0, W2s1, Wos0, Wos1,
                   Wqkvs0, Wqkvs0 + 16384, Wqkvs0 + 32768,
                   Wqkvs1, Wqkvs1 + 16384, Wqkvs1 + 32768,
                   fcWs};
  const int Ns[13]  = {FFx, FFx, Dx, Dx, Dx, Dx, Dx, Dx, Dx, Dx, Dx, Dx, Dx};
  const int kss[13] = {4, 4, 16, 16, 4, 4, 4, 4, 4, 4, 4, 4, 800};
  const int nblk[13] = {32, 32, 32, 32, 8, 8, 8, 8, 8, 8, 8, 8, 1600};
  int acc = 0;
  for (int j = 0; j < 13; ++j) {
    J.src[j] = srcs[j]; J.dst[j] = dsts[j]; J.N[j] = Ns[j]; J.ks[j] = kss[j];
    J.bstart[j] = acc; acc += nblk[j];
  }
  J.bstart[13] = acc;   // 1792
  k_cvt_all<<<acc, 256, 0, stream>>>(J);

  k_embed<<<25600, 256, 0, stream>>>(seq, tok, pos, x);
  const int cblk = BC * 200 / 64;   // 64-row blocks per chunk
  for (int i = 0; i < 2; ++i) {
    const u16* Wqkvs = (i == 0) ? Wqkvs0 : Wqkvs1;
    const u16* Wos   = (i == 0) ? Wos0 : Wos1;
    for (int c = 0; c < nc; ++c) {
      float* xc = x + (size_t)c * BC * 200 * 128;
      const int* seqc = seq + (size_t)c * BC * 200;
      k_qkv<<<cblk, 256, 0, stream>>>(xc, ln1w + i * Dx, ln1b + i * Dx, Wqkvs,
                                      bq + i * Dx, bk + i * Dx, bv + i * Dx,
                                      qb, kb, vb);
      k_attn2<<<BC * 4, 256, 0, stream>>>(qb, kb, vb, seqc, ab);
      k_oproj<<<cblk, 256, 0, stream>>>(ab, Wos, bo + i * Dx, xc);
    }
    k_ffn<<<3200, 256, 0, stream>>>(x, ln2w + i * Dx, ln2b + i * Dx,
                                    (i == 0) ? W1s0 : W1s1, b1 + i * FFx,
                                    (i == 0) ? W2s0 : W2s1, b2 + i * Dx);
  }
  k_fc<<<dim3(16, 32), 256, 0, stream>>>(x, fcWs, part);
  k_fcred<<<512, 256, 0, stream>>>(part, fcb, out);
}